// Round 2
// baseline (490.056 us; speedup 1.0000x reference)
//
#include <hip/hip_runtime.h>
#include <cstdint>

// Match XLA: no FP contraction (XLA emits separate mul/add HLOs).
#pragma clang fp contract(off)

#define TSAVES 49
#define SPSAVE 100
#define NB 8192
#define NSTEPS (TSAVES * SPSAVE)   // 4900
#define NTOT (NSTEPS * NB)         // 40140800

__device__ __forceinline__ uint32_t rotl32(uint32_t v, int d) {
  return (v << d) | (v >> (32 - d));
}

// JAX threefry2x32, 20 rounds.
__device__ __forceinline__ void tf2x32(uint32_t k0, uint32_t k1,
                                       uint32_t x0, uint32_t x1,
                                       uint32_t& o0, uint32_t& o1) {
  uint32_t ks2 = k0 ^ k1 ^ 0x1BD11BDAu;
#define TF_ROUND(r) { x0 += x1; x1 = rotl32(x1, r); x1 ^= x0; }
  x0 += k0; x1 += k1;
  TF_ROUND(13) TF_ROUND(15) TF_ROUND(26) TF_ROUND(6)
  x0 += k1; x1 += ks2 + 1u;
  TF_ROUND(17) TF_ROUND(29) TF_ROUND(16) TF_ROUND(24)
  x0 += ks2; x1 += k0 + 2u;
  TF_ROUND(13) TF_ROUND(15) TF_ROUND(26) TF_ROUND(6)
  x0 += k0; x1 += k1 + 3u;
  TF_ROUND(17) TF_ROUND(29) TF_ROUND(16) TF_ROUND(24)
  x0 += k1; x1 += ks2 + 4u;
  TF_ROUND(13) TF_ROUND(15) TF_ROUND(26) TF_ROUND(6)
  x0 += ks2; x1 += k0 + 5u;
#undef TF_ROUND
  o0 = x0; o1 = x1;
}

// jax.random.split(key(seed)) with jax_threefry_partitionable=True (modern
// default): fold-like split. Child i = (y0, y1) of threefry(key, hi=0, lo=i).
__device__ __forceinline__ void derive_keys(int seed, uint32_t& kn0, uint32_t& kn1,
                                            uint32_t& ku0, uint32_t& ku1) {
  uint64_t s = (uint64_t)(int64_t)seed;
  uint32_t k0 = (uint32_t)(s >> 32);
  uint32_t k1 = (uint32_t)(s & 0xffffffffULL);
  tf2x32(k0, k1, 0u, 0u, kn0, kn1);  // keys[0] = k_noise
  tf2x32(k0, k1, 0u, 1u, ku0, ku1);  // keys[1] = k_u
}

// partitionable random_bits(32): counter = (hi=0, lo=n); bits = y0 ^ y1.
__device__ __forceinline__ uint32_t rand_bits32(uint32_t k0, uint32_t k1, uint32_t n) {
  uint32_t y0, y1;
  tf2x32(k0, k1, 0u, n, y0, y1);
  return y0 ^ y1;
}

// bits -> dw = sqrt(DT) * (sqrt(2) * erfinv(uniform(nextafter(-1,0), 1)));
// XLA ErfInv32 (Giles), op order preserved.
__device__ __forceinline__ float bits_to_dw(uint32_t bits) {
  float u01 = __uint_as_float((bits >> 9) | 0x3f800000u) - 1.0f;
  float u = u01 * 2.0f + (-0.99999994f);  // (hi-lo) rounds to 2.0f exactly
  u = fmaxf(-0.99999994f, u);
  float w = -log1pf(-(u * u));
  float p;
  if (w < 5.0f) {
    float z = w - 2.5f;
    p = 2.81022636e-08f;
    p = 3.43273939e-07f + p * z;
    p = -3.5233877e-06f + p * z;
    p = -4.39150654e-06f + p * z;
    p = 0.00021858087f + p * z;
    p = -0.00125372503f + p * z;
    p = -0.00417768164f + p * z;
    p = 0.246640727f + p * z;
    p = 1.50140941f + p * z;
  } else {
    float z = sqrtf(w) - 3.0f;
    p = -0.000200214257f;
    p = 0.000100950558f + p * z;
    p = 0.00134934322f + p * z;
    p = -0.00367342844f + p * z;
    p = 0.00573950773f + p * z;
    p = -0.0076224613f + p * z;
    p = 0.00943887047f + p * z;
    p = 1.00167406f + p * z;
    p = 2.83297682f + p * z;
  }
  float ei = p * u;
  float nrm = 1.41421356f * ei;  // f32(np.sqrt(2))
  return nrm * 0.1f;             // * sqrt(f32(0.01)) == 0.1f exactly
}

__global__ __launch_bounds__(256) void gen_noise_kernel(const int* __restrict__ seedp,
                                                        float* __restrict__ noise) {
  __shared__ uint32_t sk[2];
  if (threadIdx.x == 0) {
    uint32_t kn0, kn1, ku0, ku1;
    derive_keys(seedp[0], kn0, kn1, ku0, ku1);
    sk[0] = kn0; sk[1] = kn1;
  }
  __syncthreads();
  uint32_t kn0 = sk[0], kn1 = sk[1];
  uint32_t n = blockIdx.x * 256u + threadIdx.x;
  if (n < (uint32_t)NTOT) {
    noise[n] = bits_to_dw(rand_bits32(kn0, kn1, n));
  }
}

__device__ __forceinline__ float clip_param(float x) {
  return fminf(0.99999988f, fmaxf(1e-07f, x));
}

template <bool FLY>
__global__ __launch_bounds__(64) void sim_kernel(const float* __restrict__ cond,
                                                 const int* __restrict__ seedp,
                                                 const float* __restrict__ noise,
                                                 float* __restrict__ out) {
  __shared__ __align__(16) float buf[2][SPSAVE * 64];
  const int lane = threadIdx.x;
  const int b0 = blockIdx.x * 64;
  const int b = b0 + lane;

  uint32_t kn0, kn1, ku0, ku1;
  derive_keys(seedp[0], kn0, kn1, ku0, ku1);

  float pinf = clip_param(cond[b * 4 + 0]);
  float prec = clip_param(cond[b * 4 + 1]);
  float pmr  = clip_param(cond[b * 4 + 2]);
  float pvol = clip_param(cond[b * 4 + 3]);

  float r0m = pinf / prec;
  float dtmr = 0.01f * pmr;

  float s = 0.99f, i = 0.01f, r0 = r0m;

  float best = -1.0f; int bi = 0;
  float plg = 0.0f, sd = 0.0f, sd2 = 0.0f;

  const int r = lane >> 4;          // row within 4-row group (width-16 staging)
  const int c = (lane & 15) << 2;   // float col within row

  if (!FLY) {
    for (int j4 = 0; j4 < 25; ++j4) {
      const float* g = noise + (size_t)(j4 * 4 + r) * NB + b0 + c;
      __builtin_amdgcn_global_load_lds(
          (const __attribute__((address_space(1))) void*)g,
          (__attribute__((address_space(3))) void*)(&buf[0][j4 * 256]),
          16, 0, 0);
    }
    __syncthreads();
  }

  for (int t = 0; t < TSAVES; ++t) {
    const int cur = t & 1;
    if (!FLY && t + 1 < TSAVES) {
      const int nxt = cur ^ 1;
      for (int j4 = 0; j4 < 25; ++j4) {
        const float* g = noise + (size_t)((t + 1) * SPSAVE + j4 * 4 + r) * NB + b0 + c;
        __builtin_amdgcn_global_load_lds(
            (const __attribute__((address_space(1))) void*)g,
            (__attribute__((address_space(3))) void*)(&buf[nxt][j4 * 256]),
            16, 0, 0);
      }
    }
#pragma unroll 10
    for (int j = 0; j < SPSAVE; ++j) {
      float dw;
      if (FLY) {
        uint32_t n = (uint32_t)(t * SPSAVE + j) * (uint32_t)NB + (uint32_t)b;
        dw = bits_to_dw(rand_bits32(kn0, kn1, n));
      } else {
        dw = buf[cur][j * 64 + lane];
      }
      // XLA op order preserved (contraction disabled file-wide):
      float ni = (r0 * prec) * s;
      float nr = prec * i;
      float s_n = s - 0.01f * ni;
      float i_n = i + 0.01f * (ni - nr);
      float r0_n = (r0 + dtmr * (r0m - r0)) + ((sqrtf(fabsf(r0)) * pvol) * dw);
      s = s_n; i = i_n; r0 = r0_n;
    }
    // save i, nan_to_num, streaming summarize
    float v = i;
    if (!isfinite(v)) v = 0.0f;
    float x = fmaxf(v, 1e-05f);
    if (x > best) { best = x; bi = t; }
    float lg = logf(x);
    if (t > 0) { float d = lg - plg; sd += d; sd2 += d * d; }
    plg = lg;
    if (!FLY) __syncthreads();
  }

  // u = uniform(k_u, (B,)) in [0,1): bits = y0^y1 of tf(ku, (0, b))
  uint32_t ub = rand_bits32(ku0, ku1, (uint32_t)b);
  float u = __uint_as_float((ub >> 9) | 0x3f800000u) - 1.0f;
  u = fmaxf(0.0f, u);

  float maxat = ((float)bi + u) / 49.0f;
  float mean = sd / 48.0f;
  float var = sd2 / 48.0f - mean * mean;
  float stdv = sqrtf(fmaxf(var, 0.0f));

  out[b * 3 + 0] = (best  - 0.38f) / 0.14f;
  out[b * 3 + 1] = (maxat - 0.21f) / 0.12f;
  out[b * 3 + 2] = (stdv  - 0.14f) / 0.03f;
}

extern "C" void kernel_launch(void* const* d_in, const int* in_sizes, int n_in,
                              void* d_out, int out_size, void* d_ws, size_t ws_size,
                              hipStream_t stream) {
  const float* cond = (const float*)d_in[0];
  const int* seedp = (const int*)d_in[1];
  float* out = (float*)d_out;
  float* noise = (float*)d_ws;
  const size_t need = (size_t)NTOT * sizeof(float);
  if (ws_size >= need) {
    gen_noise_kernel<<<(NTOT + 255) / 256, 256, 0, stream>>>(seedp, noise);
    sim_kernel<false><<<NB / 64, 64, 0, stream>>>(cond, seedp, noise, out);
  } else {
    sim_kernel<true><<<NB / 64, 64, 0, stream>>>(cond, seedp, nullptr, out);
  }
}